// Round 1
// baseline (549.416 us; speedup 1.0000x reference)
//
#include <hip/hip_runtime.h>
#include <math.h>

#define B_ 4
#define N_ 2048
#define DIM_ 3
#define H_ 128
#define K_ 32
#define L_ 4
#define OUT_ 6
#define BN_ (B_*N_)

__device__ __forceinline__ float silu_f(float x) {
    return __fdividef(x, 1.0f + __expf(-x));
}

// ---------------- embed: h = x @ ew + eb ----------------
__global__ __launch_bounds__(256) void k_embed(
    const float* __restrict__ x, const float* __restrict__ ew,
    const float* __restrict__ eb, float* __restrict__ h)
{
    int gid = blockIdx.x * 256 + threadIdx.x;   // BN_*H_ threads
    int row = gid >> 7, ch = gid & (H_-1);
    float x0 = x[row*3], x1 = x[row*3+1], x2 = x[row*3+2];
    float v = eb[ch];
    v = fmaf(x0, ew[ch], v);
    v = fmaf(x1, ew[H_+ch], v);
    v = fmaf(x2, ew[2*H_+ch], v);
    h[gid] = v;
}

// ---------------- knn: top-K smallest d^2 per row ----------------
// One wave per row; 4 rows (waves) per 256-thread block, all in one batch.
// Each lane owns j = lane + 64t (its own LDS writes only -> no intra-wave sync
// needed beyond compiler waitcnt). 32 rounds of butterfly argmin.
#define ROWS_PER_BLK 4
__global__ __launch_bounds__(256) void k_knn(
    const float* __restrict__ x, int* __restrict__ nidx, float* __restrict__ ndist)
{
    __shared__ __align__(16) float xs[N_*3];            // 24 KB
    __shared__ float ds[ROWS_PER_BLK][N_];              // 32 KB
    int b  = blockIdx.x / (N_/ROWS_PER_BLK);
    int i0 = (blockIdx.x % (N_/ROWS_PER_BLK)) * ROWS_PER_BLK;
    const float* xb = x + (size_t)b*N_*3;
    for (int t = threadIdx.x; t < N_*3; t += 256) xs[t] = xb[t];
    __syncthreads();

    int wave = threadIdx.x >> 6;
    int lane = threadIdx.x & 63;
    int i = i0 + wave;
    float xi0 = xs[i*3], xi1 = xs[i*3+1], xi2 = xs[i*3+2];
    float* drow = ds[wave];

    for (int t = 0; t < N_/64; ++t) {
        int j = lane + 64*t;
        float d0 = xi0 - xs[j*3], d1 = xi1 - xs[j*3+1], d2 = xi2 - xs[j*3+2];
        float d = d0*d0 + d1*d1 + d2*d2;
        if (j == i) d = INFINITY;
        drow[j] = d;
    }

    // per-lane argmin over its private chunk
    float lmin = INFINITY; int lix = 0;
    for (int t = 0; t < N_/64; ++t) {
        int j = lane + 64*t;
        float d = drow[j];
        if (d < lmin) { lmin = d; lix = j; }
    }

    float my_d = 0.f; int my_ix = 0;
    for (int kk = 0; kk < K_; ++kk) {
        float v = lmin; int ix = lix;
        // butterfly argmin with lowest-index tie-break
        for (int off = 32; off; off >>= 1) {
            float ov = __shfl_xor(v, off);
            int   oi = __shfl_xor(ix, off);
            if (ov < v || (ov == v && oi < ix)) { v = ov; ix = oi; }
        }
        if (lane == kk) { my_d = v; my_ix = ix; }
        if (lane == (ix & 63)) {           // winner removes + rescans its chunk
            drow[ix] = INFINITY;
            lmin = INFINITY; lix = 0;
            for (int t = 0; t < N_/64; ++t) {
                int j = lane + 64*t;
                float d = drow[j];
                if (d < lmin) { lmin = d; lix = j; }
            }
        }
    }
    if (lane < K_) {
        int r = b*N_ + i;
        nidx[(size_t)r*K_ + lane]  = my_ix;
        ndist[(size_t)r*K_ + lane] = sqrtf(fmaxf(my_d, 0.0f));
    }
}

// ---------------- per-layer: a = h@W1[0:128]+b1 ; c = h@W1[128:256] ----------------
#define M3 8
__global__ __launch_bounds__(256) void k_ac(
    const float* __restrict__ h, const float* __restrict__ w1,
    const float* __restrict__ b1, float* __restrict__ a, float* __restrict__ c)
{
    __shared__ __align__(16) float hs[M3][H_];
    int node0 = blockIdx.x * M3;
    int tid = threadIdx.x;
    int ch = tid & (H_-1);
    int which = tid >> 7;                  // 0 -> a, 1 -> c
    for (int t = tid; t < M3*H_; t += 256)
        hs[t >> 7][t & (H_-1)] = h[(size_t)node0*H_ + t];
    __syncthreads();

    float acc[M3];
#pragma unroll
    for (int m = 0; m < M3; ++m) acc[m] = 0.f;
    const float* wbase = w1 + (size_t)which * H_ * H_;
    for (int r4 = 0; r4 < H_/4; ++r4) {
        float4 hv[M3];
#pragma unroll
        for (int m = 0; m < M3; ++m)
            hv[m] = *reinterpret_cast<const float4*>(&hs[m][r4*4]);
        float w0 = wbase[(r4*4+0)*H_ + ch];
        float w1v = wbase[(r4*4+1)*H_ + ch];
        float w2v = wbase[(r4*4+2)*H_ + ch];
        float w3v = wbase[(r4*4+3)*H_ + ch];
#pragma unroll
        for (int m = 0; m < M3; ++m) {
            acc[m] = fmaf(hv[m].x, w0, acc[m]);
            acc[m] = fmaf(hv[m].y, w1v, acc[m]);
            acc[m] = fmaf(hv[m].z, w2v, acc[m]);
            acc[m] = fmaf(hv[m].w, w3v, acc[m]);
        }
    }
    float bias = (which == 0) ? b1[ch] : 0.f;
    float* dst = (which == 0) ? a : c;
#pragma unroll
    for (int m = 0; m < M3; ++m)
        dst[(size_t)(node0+m)*H_ + ch] = acc[m] + bias;
}

// ---------------- per-layer fused: edges -> agg GEMM -> update MLP -> residual ----------------
#define M4 8
#define MH (M4/2)
__global__ __launch_bounds__(256) void k_fused(
    float* __restrict__ h, const float* __restrict__ a, const float* __restrict__ c,
    const int* __restrict__ nidx, const float* __restrict__ ndist,
    const float* __restrict__ wd,   // W1 row 256 (distance weight), 128 floats
    const float* __restrict__ w2, const float* __restrict__ b2,
    const float* __restrict__ u1w, const float* __restrict__ u1b,
    const float* __restrict__ u2w, const float* __restrict__ u2b)
{
    __shared__ __align__(16) float s_lds[M4][H_];    // silu-sum; reused as t1
    __shared__ __align__(16) float agg_lds[M4][H_];
    __shared__ __align__(16) float h_lds[M4][H_];
    __shared__ int   idx_s[M4][K_];
    __shared__ float dst_s[M4][K_];
    int node0 = blockIdx.x * M4;
    int tid = threadIdx.x;
    int ch = tid & (H_-1);
    int half = tid >> 7;

    for (int t = tid; t < M4*H_; t += 256)
        h_lds[t >> 7][t & (H_-1)] = h[(size_t)node0*H_ + t];
    for (int t = tid; t < M4*K_; t += 256) {
        idx_s[t >> 5][t & (K_-1)] = nidx[(size_t)node0*K_ + t];
        dst_s[t >> 5][t & (K_-1)] = ndist[(size_t)node0*K_ + t];
    }
    __syncthreads();

    const float* cb = c + (size_t)(node0 / N_) * N_ * H_;  // batch base for gathers
    float wd_ch = wd[ch];

    // A: s[m][ch] = sum_k silu(a_i + c_j + d*wd)
#pragma unroll
    for (int mm = 0; mm < MH; ++mm) {
        int m = half*MH + mm;
        float av = a[(size_t)(node0+m)*H_ + ch];
        float sacc = 0.f;
#pragma unroll 8
        for (int k = 0; k < K_; ++k) {
            int j = idx_s[m][k];
            float dd = dst_s[m][k];
            float cv = cb[(size_t)j*H_ + ch];
            float pre = av + fmaf(dd, wd_ch, cv);
            sacc += silu_f(pre);
        }
        s_lds[m][ch] = sacc;
    }
    __syncthreads();

    // B: agg = s @ w2 + K*b2
    float aggv[MH];
#pragma unroll
    for (int mm = 0; mm < MH; ++mm) aggv[mm] = 0.f;
    for (int r4 = 0; r4 < H_/4; ++r4) {
        float4 sv[MH];
#pragma unroll
        for (int mm = 0; mm < MH; ++mm)
            sv[mm] = *reinterpret_cast<const float4*>(&s_lds[half*MH+mm][r4*4]);
        float w0 = w2[(r4*4+0)*H_+ch], w1v = w2[(r4*4+1)*H_+ch],
              w2v = w2[(r4*4+2)*H_+ch], w3v = w2[(r4*4+3)*H_+ch];
#pragma unroll
        for (int mm = 0; mm < MH; ++mm) {
            aggv[mm] = fmaf(sv[mm].x, w0, aggv[mm]);
            aggv[mm] = fmaf(sv[mm].y, w1v, aggv[mm]);
            aggv[mm] = fmaf(sv[mm].z, w2v, aggv[mm]);
            aggv[mm] = fmaf(sv[mm].w, w3v, aggv[mm]);
        }
    }
    float b2v = b2[ch] * (float)K_;
#pragma unroll
    for (int mm = 0; mm < MH; ++mm)
        agg_lds[half*MH+mm][ch] = aggv[mm] + b2v;
    __syncthreads();

    // C: t1 = silu([h, agg] @ u1w + u1b)  (store into s_lds)
    float uacc[MH];
#pragma unroll
    for (int mm = 0; mm < MH; ++mm) uacc[mm] = 0.f;
    for (int r4 = 0; r4 < H_/4; ++r4) {
        float4 hv[MH], av4[MH];
#pragma unroll
        for (int mm = 0; mm < MH; ++mm) {
            hv[mm]  = *reinterpret_cast<const float4*>(&h_lds[half*MH+mm][r4*4]);
            av4[mm] = *reinterpret_cast<const float4*>(&agg_lds[half*MH+mm][r4*4]);
        }
#pragma unroll
        for (int q = 0; q < 4; ++q) {
            int r = r4*4 + q;
            float wt = u1w[(size_t)r*H_ + ch];
            float wb = u1w[(size_t)(H_+r)*H_ + ch];
#pragma unroll
            for (int mm = 0; mm < MH; ++mm) {
                float hq = (q==0)?hv[mm].x : (q==1)?hv[mm].y : (q==2)?hv[mm].z : hv[mm].w;
                float aq = (q==0)?av4[mm].x: (q==1)?av4[mm].y: (q==2)?av4[mm].z: av4[mm].w;
                uacc[mm] = fmaf(hq, wt, uacc[mm]);
                uacc[mm] = fmaf(aq, wb, uacc[mm]);
            }
        }
    }
    float u1bv = u1b[ch];
#pragma unroll
    for (int mm = 0; mm < MH; ++mm) {
        float t1 = uacc[mm] + u1bv;
        s_lds[half*MH+mm][ch] = silu_f(t1);   // safe: phase-B reads synced already
    }
    __syncthreads();

    // D: upd = t1 @ u2w + u2b ; h += upd
    float dacc[MH];
#pragma unroll
    for (int mm = 0; mm < MH; ++mm) dacc[mm] = 0.f;
    for (int r4 = 0; r4 < H_/4; ++r4) {
        float4 tv[MH];
#pragma unroll
        for (int mm = 0; mm < MH; ++mm)
            tv[mm] = *reinterpret_cast<const float4*>(&s_lds[half*MH+mm][r4*4]);
        float w0 = u2w[(r4*4+0)*H_+ch], w1v = u2w[(r4*4+1)*H_+ch],
              w2v = u2w[(r4*4+2)*H_+ch], w3v = u2w[(r4*4+3)*H_+ch];
#pragma unroll
        for (int mm = 0; mm < MH; ++mm) {
            dacc[mm] = fmaf(tv[mm].x, w0, dacc[mm]);
            dacc[mm] = fmaf(tv[mm].y, w1v, dacc[mm]);
            dacc[mm] = fmaf(tv[mm].z, w2v, dacc[mm]);
            dacc[mm] = fmaf(tv[mm].w, w3v, dacc[mm]);
        }
    }
    float u2bv = u2b[ch];
#pragma unroll
    for (int mm = 0; mm < MH; ++mm) {
        int m = half*MH + mm;
        h[(size_t)(node0+m)*H_ + ch] = h_lds[m][ch] + dacc[mm] + u2bv;
    }
}

// ---------------- out: out = h @ ow + ob ----------------
__global__ __launch_bounds__(256) void k_out(
    const float* __restrict__ h, const float* __restrict__ ow,
    const float* __restrict__ ob, float* __restrict__ out)
{
    int gid = blockIdx.x * 256 + threadIdx.x;  // BN_*8 threads
    int node = gid >> 3, o = gid & 7;
    if (o < OUT_) {
        float acc = ob[o];
        const float* hrow = h + (size_t)node*H_;
        for (int r = 0; r < H_; ++r)
            acc = fmaf(hrow[r], ow[r*OUT_ + o], acc);
        out[(size_t)node*OUT_ + o] = acc;
    }
}

extern "C" void kernel_launch(void* const* d_in, const int* in_sizes, int n_in,
                              void* d_out, int out_size, void* d_ws, size_t ws_size,
                              hipStream_t stream)
{
    const float* x   = (const float*)d_in[0];
    const float* ew  = (const float*)d_in[1];
    const float* eb  = (const float*)d_in[2];
    const float* miw = (const float*)d_in[3];   // (L,257,H)
    const float* mib = (const float*)d_in[4];   // (L,H)
    const float* mow = (const float*)d_in[5];   // (L,H,H)
    const float* mob = (const float*)d_in[6];   // (L,H)
    const float* uiw = (const float*)d_in[7];   // (L,2H,H)
    const float* uib = (const float*)d_in[8];   // (L,H)
    const float* uow = (const float*)d_in[9];   // (L,H,H)
    const float* uob = (const float*)d_in[10];  // (L,H)
    const float* ow  = (const float*)d_in[11];  // (H,OUT)
    const float* ob  = (const float*)d_in[12];  // (OUT)
    float* out = (float*)d_out;

    // workspace layout (floats): h | a | c | ndist | nidx  (~14 MB total)
    float* ws = (float*)d_ws;
    float* h  = ws;
    float* a  = ws + (size_t)BN_*H_;
    float* c  = ws + 2ull*BN_*H_;
    float* nd = ws + 3ull*BN_*H_;
    int*   ni = (int*)(ws + 3ull*BN_*H_ + (size_t)BN_*K_);

    k_embed<<<BN_*H_/256, 256, 0, stream>>>(x, ew, eb, h);
    k_knn<<<BN_/ROWS_PER_BLK, 256, 0, stream>>>(x, ni, nd);
    for (int l = 0; l < L_; ++l) {
        const float* w1 = miw + (size_t)l*257*H_;
        k_ac<<<BN_/M3, 256, 0, stream>>>(h, w1, mib + (size_t)l*H_, a, c);
        k_fused<<<BN_/M4, 256, 0, stream>>>(h, a, c, ni, nd,
            w1 + 256*H_,
            mow + (size_t)l*H_*H_, mob + (size_t)l*H_,
            uiw + (size_t)l*2*H_*H_, uib + (size_t)l*H_,
            uow + (size_t)l*H_*H_, uob + (size_t)l*H_);
    }
    k_out<<<BN_*8/256, 256, 0, stream>>>(h, ow, ob, out);
}

// Round 2
// 443.132 us; speedup vs baseline: 1.2398x; 1.2398x over previous
//
#include <hip/hip_runtime.h>
#include <math.h>

#define B_ 4
#define N_ 2048
#define DIM_ 3
#define H_ 128
#define K_ 32
#define L_ 4
#define OUT_ 6
#define BN_ (B_*N_)

__device__ __forceinline__ float silu_f(float x) {
    return __fdividef(x, 1.0f + __expf(-x));
}

// ---------------- embed: h = x @ ew + eb ----------------
__global__ __launch_bounds__(256) void k_embed(
    const float* __restrict__ x, const float* __restrict__ ew,
    const float* __restrict__ eb, float* __restrict__ h)
{
    int gid = blockIdx.x * 256 + threadIdx.x;   // BN_*H_ threads
    int row = gid >> 7, ch = gid & (H_-1);
    float x0 = x[row*3], x1 = x[row*3+1], x2 = x[row*3+2];
    float v = eb[ch];
    v = fmaf(x0, ew[ch], v);
    v = fmaf(x1, ew[H_+ch], v);
    v = fmaf(x2, ew[2*H_+ch], v);
    h[gid] = v;
}

// ---------------- knn: radix-select top-K smallest d^2 per row ----------------
// One wave per row, 4 rows/block. Keys = float bits of d^2 (non-negative ->
// uint order == float order). 4 passes x 8 bits: histogram into per-wave LDS
// bins, scan bins for the digit containing the K-th smallest, refine. After
// 4 passes we hold the exact K-th key T; collect u<T plus `need` ties.
// Output ORDER is irrelevant downstream (sum over k), so no sorting.
#define KNN_ROWS 4
__global__ __launch_bounds__(256) void k_knn(
    const float* __restrict__ x, int* __restrict__ nidx, float* __restrict__ ndist)
{
    __shared__ __align__(16) float4 xs[N_];       // 32 KB (x,y,z,pad)
    __shared__ int hist[KNN_ROWS][256];           // 4 KB
    __shared__ int cnt_lt[KNN_ROWS], cnt_eq[KNN_ROWS];
    int b  = blockIdx.x / (N_/KNN_ROWS);
    int i0 = (blockIdx.x % (N_/KNN_ROWS)) * KNN_ROWS;
    const float* xb = x + (size_t)b*N_*3;
    for (int t = threadIdx.x; t < N_; t += 256)
        xs[t] = make_float4(xb[t*3], xb[t*3+1], xb[t*3+2], 0.f);
    __syncthreads();

    int wave = threadIdx.x >> 6, lane = threadIdx.x & 63;
    int i = i0 + wave;
    float4 xi = xs[i];
    int* hrow = hist[wave];

    unsigned u[N_/64];                 // 32 keys per lane, j = lane + 64*t
#pragma unroll
    for (int t = 0; t < N_/64; ++t) {
        int j = lane + 64*t;
        float4 xj = xs[j];
        float d0 = xi.x-xj.x, d1 = xi.y-xj.y, d2 = xi.z-xj.z;
        float d = d0*d0 + d1*d1 + d2*d2;
        u[t] = (j == i) ? 0x7F800000u : __float_as_uint(d);
    }

    unsigned prefix = 0, pmask = 0;
    int need = K_;
    for (int pass = 0; pass < 4; ++pass) {
        int s = 24 - pass*8;
        for (int bb = lane; bb < 256; bb += 64) hrow[bb] = 0;
        __syncthreads();
#pragma unroll
        for (int t = 0; t < N_/64; ++t)
            if ((u[t] & pmask) == prefix)
                atomicAdd(&hrow[(u[t] >> s) & 255], 1);
        __syncthreads();
        // scan 256 bins: 4 per lane, wave prefix-scan of lane sums
        int c0 = hrow[lane*4+0], c1 = hrow[lane*4+1],
            c2 = hrow[lane*4+2], c3 = hrow[lane*4+3];
        int lsum = c0 + c1 + c2 + c3;
        int scan = lsum;
        for (int off = 1; off < 64; off <<= 1) {
            int o = __shfl_up(scan, off);
            if (lane >= off) scan += o;
        }
        int incl = scan, excl = incl - lsum;
        int D = -1, less = 0;
        if (excl < need && need <= incl) {
            if      (excl + c0 >= need)           { D = lane*4+0; less = excl; }
            else if (excl + c0 + c1 >= need)      { D = lane*4+1; less = excl + c0; }
            else if (excl + c0 + c1 + c2 >= need) { D = lane*4+2; less = excl + c0 + c1; }
            else                                  { D = lane*4+3; less = excl + c0 + c1 + c2; }
        }
        int packed = (D >= 0) ? ((D << 16) | less) : -1;
        for (int off = 32; off; off >>= 1)
            packed = max(packed, __shfl_xor(packed, off));
        D = packed >> 16; less = packed & 0xFFFF;
        prefix |= ((unsigned)D) << s;
        pmask  |= 0xFFu << s;
        need -= less;
        __syncthreads();
    }
    // prefix == exact key of the K-th smallest; need = #ties to take (>=1)
    if (lane == 0) { cnt_lt[wave] = 0; cnt_eq[wave] = 0; }
    __syncthreads();
    int base_eq = K_ - need;
    size_t rbase = ((size_t)(b*N_ + i)) * K_;
#pragma unroll
    for (int t = 0; t < N_/64; ++t) {
        int pos = -1;
        if (u[t] < prefix) {
            pos = atomicAdd(&cnt_lt[wave], 1);
        } else if (u[t] == prefix) {
            int e = atomicAdd(&cnt_eq[wave], 1);
            if (e < need) pos = base_eq + e;
        }
        if (pos >= 0) {
            nidx[rbase + pos]  = lane + 64*t;
            ndist[rbase + pos] = sqrtf(__uint_as_float(u[t]));
        }
    }
}

// ---------------- per-layer: a = h@W1[0:128]+b1 ; c = h@W1[128:256] ----------------
#define M3 8
__global__ __launch_bounds__(256) void k_ac(
    const float* __restrict__ h, const float* __restrict__ w1,
    const float* __restrict__ b1, float* __restrict__ a, float* __restrict__ c)
{
    __shared__ __align__(16) float hs[M3][H_];
    int node0 = blockIdx.x * M3;
    int tid = threadIdx.x;
    int ch = tid & (H_-1);
    int which = tid >> 7;                  // 0 -> a, 1 -> c
    for (int t = tid; t < M3*H_; t += 256)
        hs[t >> 7][t & (H_-1)] = h[(size_t)node0*H_ + t];
    __syncthreads();

    float acc[M3];
#pragma unroll
    for (int m = 0; m < M3; ++m) acc[m] = 0.f;
    const float* wbase = w1 + (size_t)which * H_ * H_;
    for (int r4 = 0; r4 < H_/4; ++r4) {
        float4 hv[M3];
#pragma unroll
        for (int m = 0; m < M3; ++m)
            hv[m] = *reinterpret_cast<const float4*>(&hs[m][r4*4]);
        float w0 = wbase[(r4*4+0)*H_ + ch];
        float w1v = wbase[(r4*4+1)*H_ + ch];
        float w2v = wbase[(r4*4+2)*H_ + ch];
        float w3v = wbase[(r4*4+3)*H_ + ch];
#pragma unroll
        for (int m = 0; m < M3; ++m) {
            acc[m] = fmaf(hv[m].x, w0, acc[m]);
            acc[m] = fmaf(hv[m].y, w1v, acc[m]);
            acc[m] = fmaf(hv[m].z, w2v, acc[m]);
            acc[m] = fmaf(hv[m].w, w3v, acc[m]);
        }
    }
    float bias = (which == 0) ? b1[ch] : 0.f;
    float* dst = (which == 0) ? a : c;
#pragma unroll
    for (int m = 0; m < M3; ++m)
        dst[(size_t)(node0+m)*H_ + ch] = acc[m] + bias;
}

// ---------------- per-layer fused: edges -> agg GEMM -> update MLP -> residual ----------------
#define M4 8
#define MH (M4/2)
__global__ __launch_bounds__(256) void k_fused(
    float* __restrict__ h, const float* __restrict__ a, const float* __restrict__ c,
    const int* __restrict__ nidx, const float* __restrict__ ndist,
    const float* __restrict__ wd,   // W1 row 256 (distance weight), 128 floats
    const float* __restrict__ w2, const float* __restrict__ b2,
    const float* __restrict__ u1w, const float* __restrict__ u1b,
    const float* __restrict__ u2w, const float* __restrict__ u2b)
{
    __shared__ __align__(16) float s_lds[M4][H_];    // silu-sum; reused as t1
    __shared__ __align__(16) float agg_lds[M4][H_];
    __shared__ __align__(16) float h_lds[M4][H_];
    __shared__ int   idx_s[M4][K_];
    __shared__ float dst_s[M4][K_];
    int node0 = blockIdx.x * M4;
    int tid = threadIdx.x;
    int ch = tid & (H_-1);
    int half = tid >> 7;

    for (int t = tid; t < M4*H_; t += 256)
        h_lds[t >> 7][t & (H_-1)] = h[(size_t)node0*H_ + t];
    for (int t = tid; t < M4*K_; t += 256) {
        idx_s[t >> 5][t & (K_-1)] = nidx[(size_t)node0*K_ + t];
        dst_s[t >> 5][t & (K_-1)] = ndist[(size_t)node0*K_ + t];
    }
    __syncthreads();

    const float* cb = c + (size_t)(node0 / N_) * N_ * H_;  // batch base for gathers
    float wd_ch = wd[ch];

    // A: s[m][ch] = sum_k silu(a_i + c_j + d*wd)
#pragma unroll
    for (int mm = 0; mm < MH; ++mm) {
        int m = half*MH + mm;
        float av = a[(size_t)(node0+m)*H_ + ch];
        float sacc = 0.f;
#pragma unroll 8
        for (int k = 0; k < K_; ++k) {
            int j = idx_s[m][k];
            float dd = dst_s[m][k];
            float cv = cb[(size_t)j*H_ + ch];
            float pre = av + fmaf(dd, wd_ch, cv);
            sacc += silu_f(pre);
        }
        s_lds[m][ch] = sacc;
    }
    __syncthreads();

    // B: agg = s @ w2 + K*b2
    float aggv[MH];
#pragma unroll
    for (int mm = 0; mm < MH; ++mm) aggv[mm] = 0.f;
    for (int r4 = 0; r4 < H_/4; ++r4) {
        float4 sv[MH];
#pragma unroll
        for (int mm = 0; mm < MH; ++mm)
            sv[mm] = *reinterpret_cast<const float4*>(&s_lds[half*MH+mm][r4*4]);
        float w0 = w2[(r4*4+0)*H_+ch], w1v = w2[(r4*4+1)*H_+ch],
              w2v = w2[(r4*4+2)*H_+ch], w3v = w2[(r4*4+3)*H_+ch];
#pragma unroll
        for (int mm = 0; mm < MH; ++mm) {
            aggv[mm] = fmaf(sv[mm].x, w0, aggv[mm]);
            aggv[mm] = fmaf(sv[mm].y, w1v, aggv[mm]);
            aggv[mm] = fmaf(sv[mm].z, w2v, aggv[mm]);
            aggv[mm] = fmaf(sv[mm].w, w3v, aggv[mm]);
        }
    }
    float b2v = b2[ch] * (float)K_;
#pragma unroll
    for (int mm = 0; mm < MH; ++mm)
        agg_lds[half*MH+mm][ch] = aggv[mm] + b2v;
    __syncthreads();

    // C: t1 = silu([h, agg] @ u1w + u1b)  (store into s_lds)
    float uacc[MH];
#pragma unroll
    for (int mm = 0; mm < MH; ++mm) uacc[mm] = 0.f;
    for (int r4 = 0; r4 < H_/4; ++r4) {
        float4 hv[MH], av4[MH];
#pragma unroll
        for (int mm = 0; mm < MH; ++mm) {
            hv[mm]  = *reinterpret_cast<const float4*>(&h_lds[half*MH+mm][r4*4]);
            av4[mm] = *reinterpret_cast<const float4*>(&agg_lds[half*MH+mm][r4*4]);
        }
#pragma unroll
        for (int q = 0; q < 4; ++q) {
            int r = r4*4 + q;
            float wt = u1w[(size_t)r*H_ + ch];
            float wb = u1w[(size_t)(H_+r)*H_ + ch];
#pragma unroll
            for (int mm = 0; mm < MH; ++mm) {
                float hq = (q==0)?hv[mm].x : (q==1)?hv[mm].y : (q==2)?hv[mm].z : hv[mm].w;
                float aq = (q==0)?av4[mm].x: (q==1)?av4[mm].y: (q==2)?av4[mm].z: av4[mm].w;
                uacc[mm] = fmaf(hq, wt, uacc[mm]);
                uacc[mm] = fmaf(aq, wb, uacc[mm]);
            }
        }
    }
    float u1bv = u1b[ch];
#pragma unroll
    for (int mm = 0; mm < MH; ++mm) {
        float t1 = uacc[mm] + u1bv;
        s_lds[half*MH+mm][ch] = silu_f(t1);
    }
    __syncthreads();

    // D: upd = t1 @ u2w + u2b ; h += upd
    float dacc[MH];
#pragma unroll
    for (int mm = 0; mm < MH; ++mm) dacc[mm] = 0.f;
    for (int r4 = 0; r4 < H_/4; ++r4) {
        float4 tv[MH];
#pragma unroll
        for (int mm = 0; mm < MH; ++mm)
            tv[mm] = *reinterpret_cast<const float4*>(&s_lds[half*MH+mm][r4*4]);
        float w0 = u2w[(r4*4+0)*H_+ch], w1v = u2w[(r4*4+1)*H_+ch],
              w2v = u2w[(r4*4+2)*H_+ch], w3v = u2w[(r4*4+3)*H_+ch];
#pragma unroll
        for (int mm = 0; mm < MH; ++mm) {
            dacc[mm] = fmaf(tv[mm].x, w0, dacc[mm]);
            dacc[mm] = fmaf(tv[mm].y, w1v, dacc[mm]);
            dacc[mm] = fmaf(tv[mm].z, w2v, dacc[mm]);
            dacc[mm] = fmaf(tv[mm].w, w3v, dacc[mm]);
        }
    }
    float u2bv = u2b[ch];
#pragma unroll
    for (int mm = 0; mm < MH; ++mm) {
        int m = half*MH + mm;
        h[(size_t)(node0+m)*H_ + ch] = h_lds[m][ch] + dacc[mm] + u2bv;
    }
}

// ---------------- out: out = h @ ow + ob ----------------
__global__ __launch_bounds__(256) void k_out(
    const float* __restrict__ h, const float* __restrict__ ow,
    const float* __restrict__ ob, float* __restrict__ out)
{
    int gid = blockIdx.x * 256 + threadIdx.x;  // BN_*8 threads
    int node = gid >> 3, o = gid & 7;
    if (o < OUT_) {
        float acc = ob[o];
        const float* hrow = h + (size_t)node*H_;
        for (int r = 0; r < H_; ++r)
            acc = fmaf(hrow[r], ow[r*OUT_ + o], acc);
        out[(size_t)node*OUT_ + o] = acc;
    }
}

extern "C" void kernel_launch(void* const* d_in, const int* in_sizes, int n_in,
                              void* d_out, int out_size, void* d_ws, size_t ws_size,
                              hipStream_t stream)
{
    const float* x   = (const float*)d_in[0];
    const float* ew  = (const float*)d_in[1];
    const float* eb  = (const float*)d_in[2];
    const float* miw = (const float*)d_in[3];   // (L,257,H)
    const float* mib = (const float*)d_in[4];   // (L,H)
    const float* mow = (const float*)d_in[5];   // (L,H,H)
    const float* mob = (const float*)d_in[6];   // (L,H)
    const float* uiw = (const float*)d_in[7];   // (L,2H,H)
    const float* uib = (const float*)d_in[8];   // (L,H)
    const float* uow = (const float*)d_in[9];   // (L,H,H)
    const float* uob = (const float*)d_in[10];  // (L,H)
    const float* ow  = (const float*)d_in[11];  // (H,OUT)
    const float* ob  = (const float*)d_in[12];  // (OUT)
    float* out = (float*)d_out;

    // workspace layout (floats): h | a | c | ndist | nidx  (~14 MB total)
    float* ws = (float*)d_ws;
    float* h  = ws;
    float* a  = ws + (size_t)BN_*H_;
    float* c  = ws + 2ull*BN_*H_;
    float* nd = ws + 3ull*BN_*H_;
    int*   ni = (int*)(ws + 3ull*BN_*H_ + (size_t)BN_*K_);

    k_embed<<<BN_*H_/256, 256, 0, stream>>>(x, ew, eb, h);
    k_knn<<<BN_/KNN_ROWS, 256, 0, stream>>>(x, ni, nd);
    for (int l = 0; l < L_; ++l) {
        const float* w1 = miw + (size_t)l*257*H_;
        k_ac<<<BN_/M3, 256, 0, stream>>>(h, w1, mib + (size_t)l*H_, a, c);
        k_fused<<<BN_/M4, 256, 0, stream>>>(h, a, c, ni, nd,
            w1 + 256*H_,
            mow + (size_t)l*H_*H_, mob + (size_t)l*H_,
            uiw + (size_t)l*2*H_*H_, uib + (size_t)l*H_,
            uow + (size_t)l*H_*H_, uob + (size_t)l*H_);
    }
    k_out<<<BN_*8/256, 256, 0, stream>>>(h, ow, ob, out);
}

// Round 3
// 338.501 us; speedup vs baseline: 1.6231x; 1.3091x over previous
//
#include <hip/hip_runtime.h>
#include <math.h>

#define B_ 4
#define N_ 2048
#define DIM_ 3
#define H_ 128
#define K_ 32
#define L_ 4
#define OUT_ 6
#define BN_ (B_*N_)

typedef __attribute__((ext_vector_type(8))) short short8;
typedef __attribute__((ext_vector_type(4))) float f32x4;

#define LDW (H_ + 8)          // padded LDS row (bf16 elems): +16B keeps b128 alignment, tiles banks 2-way
#define LAYER_W 98304         // shorts per layer: w1a 16K | w1c 16K | w2 16K | u1 32K | u2 16K
#define OFF_W1A 0
#define OFF_W1C 16384
#define OFF_W2  32768
#define OFF_U1  49152
#define OFF_U2  81920

__device__ __forceinline__ float silu_f(float x) {
    return __fdividef(x, 1.0f + __expf(-x));
}
__device__ __forceinline__ short f2b(float f) {          // fp32 -> bf16 RNE
    unsigned u = __float_as_uint(f);
    return (short)((u + 0x7FFFu + ((u >> 16) & 1u)) >> 16);
}
__device__ __forceinline__ float b2f(short s) {
    return __uint_as_float(((unsigned)(unsigned short)s) << 16);
}
__device__ __forceinline__ unsigned pack2(short lo, short hi) {
    return (unsigned)(unsigned short)lo | ((unsigned)(unsigned short)hi << 16);
}

// ---------------- prep: transpose+cast all layer weights to bf16 [n][k] ----------------
__global__ __launch_bounds__(256) void k_prep(
    const float* __restrict__ miw, const float* __restrict__ mow,
    const float* __restrict__ uiw, const float* __restrict__ uow,
    short* __restrict__ wt)
{
    int gid = blockIdx.x * 256 + threadIdx.x;      // L_*LAYER_W threads exactly
    int l = gid / LAYER_W, o = gid - l * LAYER_W;
    float v;
    if (o < OFF_W1C) {
        int n = o >> 7, k = o & 127;
        v = miw[(size_t)l*257*H_ + k*H_ + n];
    } else if (o < OFF_W2) {
        int oo = o - OFF_W1C, n = oo >> 7, k = oo & 127;
        v = miw[(size_t)l*257*H_ + (128 + k)*H_ + n];
    } else if (o < OFF_U1) {
        int oo = o - OFF_W2, n = oo >> 7, k = oo & 127;
        v = mow[(size_t)l*H_*H_ + k*H_ + n];
    } else if (o < OFF_U2) {
        int oo = o - OFF_U1, n = oo >> 8, k = oo & 255;
        v = uiw[(size_t)l*2*H_*H_ + k*H_ + n];
    } else {
        int oo = o - OFF_U2, n = oo >> 7, k = oo & 127;
        v = uow[(size_t)l*H_*H_ + k*H_ + n];
    }
    wt[gid] = f2b(v);
}

// ---------------- embed: h = x @ ew + eb ----------------
__global__ __launch_bounds__(256) void k_embed(
    const float* __restrict__ x, const float* __restrict__ ew,
    const float* __restrict__ eb, float* __restrict__ h)
{
    int gid = blockIdx.x * 256 + threadIdx.x;   // BN_*H_ threads
    int row = gid >> 7, ch = gid & (H_-1);
    float x0 = x[row*3], x1 = x[row*3+1], x2 = x[row*3+2];
    float v = eb[ch];
    v = fmaf(x0, ew[ch], v);
    v = fmaf(x1, ew[H_+ch], v);
    v = fmaf(x2, ew[2*H_+ch], v);
    h[gid] = v;
}

// ---------------- knn: radix-select top-K smallest d^2 per row ----------------
#define KNN_ROWS 4
__global__ __launch_bounds__(256) void k_knn(
    const float* __restrict__ x, int* __restrict__ nidx, float* __restrict__ ndist)
{
    __shared__ __align__(16) float4 xs[N_];
    __shared__ int hist[KNN_ROWS][256];
    __shared__ int cnt_lt[KNN_ROWS], cnt_eq[KNN_ROWS];
    int b  = blockIdx.x / (N_/KNN_ROWS);
    int i0 = (blockIdx.x % (N_/KNN_ROWS)) * KNN_ROWS;
    const float* xb = x + (size_t)b*N_*3;
    for (int t = threadIdx.x; t < N_; t += 256)
        xs[t] = make_float4(xb[t*3], xb[t*3+1], xb[t*3+2], 0.f);
    __syncthreads();

    int wave = threadIdx.x >> 6, lane = threadIdx.x & 63;
    int i = i0 + wave;
    float4 xi = xs[i];
    int* hrow = hist[wave];

    unsigned u[N_/64];
#pragma unroll
    for (int t = 0; t < N_/64; ++t) {
        int j = lane + 64*t;
        float4 xj = xs[j];
        float d0 = xi.x-xj.x, d1 = xi.y-xj.y, d2 = xi.z-xj.z;
        float d = d0*d0 + d1*d1 + d2*d2;
        u[t] = (j == i) ? 0x7F800000u : __float_as_uint(d);
    }

    unsigned prefix = 0, pmask = 0;
    int need = K_;
    for (int pass = 0; pass < 4; ++pass) {
        int s = 24 - pass*8;
        for (int bb = lane; bb < 256; bb += 64) hrow[bb] = 0;
        __syncthreads();
#pragma unroll
        for (int t = 0; t < N_/64; ++t)
            if ((u[t] & pmask) == prefix)
                atomicAdd(&hrow[(u[t] >> s) & 255], 1);
        __syncthreads();
        int c0 = hrow[lane*4+0], c1 = hrow[lane*4+1],
            c2 = hrow[lane*4+2], c3 = hrow[lane*4+3];
        int lsum = c0 + c1 + c2 + c3;
        int scan = lsum;
        for (int off = 1; off < 64; off <<= 1) {
            int o = __shfl_up(scan, off);
            if (lane >= off) scan += o;
        }
        int incl = scan, excl = incl - lsum;
        int D = -1, less = 0;
        if (excl < need && need <= incl) {
            if      (excl + c0 >= need)           { D = lane*4+0; less = excl; }
            else if (excl + c0 + c1 >= need)      { D = lane*4+1; less = excl + c0; }
            else if (excl + c0 + c1 + c2 >= need) { D = lane*4+2; less = excl + c0 + c1; }
            else                                  { D = lane*4+3; less = excl + c0 + c1 + c2; }
        }
        int packed = (D >= 0) ? ((D << 16) | less) : -1;
        for (int off = 32; off; off >>= 1)
            packed = max(packed, __shfl_xor(packed, off));
        D = packed >> 16; less = packed & 0xFFFF;
        prefix |= ((unsigned)D) << s;
        pmask  |= 0xFFu << s;
        need -= less;
        __syncthreads();
    }
    if (lane == 0) { cnt_lt[wave] = 0; cnt_eq[wave] = 0; }
    __syncthreads();
    int base_eq = K_ - need;
    size_t rbase = ((size_t)(b*N_ + i)) * K_;
#pragma unroll
    for (int t = 0; t < N_/64; ++t) {
        int pos = -1;
        if (u[t] < prefix) {
            pos = atomicAdd(&cnt_lt[wave], 1);
        } else if (u[t] == prefix) {
            int e = atomicAdd(&cnt_eq[wave], 1);
            if (e < need) pos = base_eq + e;
        }
        if (pos >= 0) {
            nidx[rbase + pos]  = lane + 64*t;
            ndist[rbase + pos] = sqrtf(__uint_as_float(u[t]));
        }
    }
}

// ---------------- k_ac (MFMA): a = h@W1a + b1 ; c = h@W1c  (both bf16 out) ----------------
#define MAC 32
__global__ __launch_bounds__(256) void k_ac(
    const float* __restrict__ h, const short* __restrict__ wt1a,
    const short* __restrict__ wt1c, const float* __restrict__ b1,
    short* __restrict__ a, short* __restrict__ c)
{
    __shared__ __align__(16) short h_l[MAC][LDW];
    int node0 = blockIdx.x * MAC;
    int tid = threadIdx.x;
    // stage h (fp32) -> bf16 LDS, float4 loads
    for (int t = tid; t < MAC*H_/4; t += 256) {
        float4 v = reinterpret_cast<const float4*>(h + (size_t)node0*H_)[t];
        int row = t >> 5, col = (t & 31) * 4;
        h_l[row][col+0] = f2b(v.x); h_l[row][col+1] = f2b(v.y);
        h_l[row][col+2] = f2b(v.z); h_l[row][col+3] = f2b(v.w);
    }
    __syncthreads();

    int wave = tid >> 6, lane = tid & 63, l15 = lane & 15, quad = lane >> 4;
    f32x4 accA[2][2], accC[2][2];
#pragma unroll
    for (int rt = 0; rt < 2; ++rt)
#pragma unroll
        for (int ct = 0; ct < 2; ++ct) {
            accA[rt][ct] = (f32x4){0.f,0.f,0.f,0.f};
            accC[rt][ct] = (f32x4){0.f,0.f,0.f,0.f};
        }
    int colbase = wave * 32;
#pragma unroll
    for (int kk = 0; kk < 4; ++kk) {
        int k0 = kk*32 + quad*8;
        short8 af[2];
        af[0] = *(const short8*)&h_l[l15][k0];
        af[1] = *(const short8*)&h_l[16 + l15][k0];
#pragma unroll
        for (int ct = 0; ct < 2; ++ct) {
            int n = colbase + ct*16 + l15;
            short8 bA = *(const short8*)(wt1a + (size_t)n*H_ + k0);
            short8 bC = *(const short8*)(wt1c + (size_t)n*H_ + k0);
#pragma unroll
            for (int rt = 0; rt < 2; ++rt) {
                accA[rt][ct] = __builtin_amdgcn_mfma_f32_16x16x32_bf16(af[rt], bA, accA[rt][ct], 0, 0, 0);
                accC[rt][ct] = __builtin_amdgcn_mfma_f32_16x16x32_bf16(af[rt], bC, accC[rt][ct], 0, 0, 0);
            }
        }
    }
#pragma unroll
    for (int ct = 0; ct < 2; ++ct) {
        int n = colbase + ct*16 + l15;
        float b1v = b1[n];
#pragma unroll
        for (int rt = 0; rt < 2; ++rt)
#pragma unroll
            for (int r = 0; r < 4; ++r) {
                int m = rt*16 + quad*4 + r;
                size_t gi = (size_t)(node0+m)*H_ + n;
                a[gi] = f2b(accA[rt][ct][r] + b1v);
                c[gi] = f2b(accC[rt][ct][r]);
            }
    }
}

// ---------------- k_edge: s[m][ch] = sum_k silu(a_i + c_j + d*wd)  (bf16 out) ----------------
#define ME 8
__global__ __launch_bounds__(256) void k_edge(
    const unsigned* __restrict__ a2, const unsigned* __restrict__ c2,
    const int* __restrict__ nidx, const float* __restrict__ ndist,
    const float* __restrict__ wd, unsigned* __restrict__ s2)
{
    __shared__ int idx_s[ME][K_];
    __shared__ float dst_s[ME][K_];
    int node0 = blockIdx.x * ME;
    int tid = threadIdx.x;
    for (int t = tid; t < ME*K_; t += 256) {
        idx_s[t>>5][t&31] = nidx[(size_t)node0*K_ + t];
        dst_s[t>>5][t&31] = ndist[(size_t)node0*K_ + t];
    }
    __syncthreads();
    int c2i = tid & 63;                 // uint index (2 channels)
    int grp = tid >> 6;                 // 0..3
    int ch0 = c2i * 2;
    float wd0 = wd[ch0], wd1 = wd[ch0+1];
    size_t cbase2 = (size_t)(node0 / N_) * N_ * (H_/2);
#pragma unroll
    for (int mm = 0; mm < 2; ++mm) {
        int m = grp*2 + mm;
        unsigned av = a2[(size_t)(node0+m)*(H_/2) + c2i];
        float a0 = b2f((short)(av & 0xFFFFu)), a1 = b2f((short)(av >> 16));
        float s0 = 0.f, s1 = 0.f;
#pragma unroll 8
        for (int k = 0; k < K_; ++k) {
            int j = idx_s[m][k];
            float dd = dst_s[m][k];
            unsigned cv = c2[cbase2 + (size_t)j*(H_/2) + c2i];
            float cv0 = b2f((short)(cv & 0xFFFFu)), cv1 = b2f((short)(cv >> 16));
            s0 += silu_f(a0 + fmaf(dd, wd0, cv0));
            s1 += silu_f(a1 + fmaf(dd, wd1, cv1));
        }
        s2[(size_t)(node0+m)*(H_/2) + c2i] = pack2(f2b(s0), f2b(s1));
    }
}

// ---------------- k_upd (MFMA x3): agg = s@w2+K*b2 ; t1 = silu([h,agg]@u1+u1b) ;
//                  h += t1@u2 + u2b (residual in fp32) ----------------
#define MU 32
__global__ __launch_bounds__(256) void k_upd(
    float* __restrict__ h, const short* __restrict__ s,
    const short* __restrict__ wt2, const float* __restrict__ b2,
    const short* __restrict__ wtu1, const float* __restrict__ u1b,
    const short* __restrict__ wtu2, const float* __restrict__ u2b)
{
    __shared__ __align__(16) short s_l[MU][LDW];     // s; later reused for t1
    __shared__ __align__(16) short h_l[MU][LDW];
    __shared__ __align__(16) short agg_l[MU][LDW];
    int node0 = blockIdx.x * MU;
    int tid = threadIdx.x;
    // stage h (fp32->bf16) and s (bf16 copy)
    for (int t = tid; t < MU*H_/4; t += 256) {
        float4 v = reinterpret_cast<const float4*>(h + (size_t)node0*H_)[t];
        int row = t >> 5, col = (t & 31) * 4;
        h_l[row][col+0] = f2b(v.x); h_l[row][col+1] = f2b(v.y);
        h_l[row][col+2] = f2b(v.z); h_l[row][col+3] = f2b(v.w);
    }
    for (int t = tid; t < MU*H_/2; t += 256) {
        unsigned v = reinterpret_cast<const unsigned*>(s + (size_t)node0*H_)[t];
        int row = t >> 6, col = (t & 63) * 2;
        s_l[row][col]   = (short)(v & 0xFFFFu);
        s_l[row][col+1] = (short)(v >> 16);
    }
    __syncthreads();

    int wave = tid >> 6, lane = tid & 63, l15 = lane & 15, quad = lane >> 4;
    int colbase = wave * 32;
    f32x4 acc[2][2];

    // ---- GEMM1: agg = s @ w2 + K*b2 ----
#pragma unroll
    for (int rt = 0; rt < 2; ++rt)
#pragma unroll
        for (int ct = 0; ct < 2; ++ct) acc[rt][ct] = (f32x4){0.f,0.f,0.f,0.f};
#pragma unroll
    for (int kk = 0; kk < 4; ++kk) {
        int k0 = kk*32 + quad*8;
        short8 af0 = *(const short8*)&s_l[l15][k0];
        short8 af1 = *(const short8*)&s_l[16 + l15][k0];
#pragma unroll
        for (int ct = 0; ct < 2; ++ct) {
            int n = colbase + ct*16 + l15;
            short8 bf = *(const short8*)(wt2 + (size_t)n*H_ + k0);
            acc[0][ct] = __builtin_amdgcn_mfma_f32_16x16x32_bf16(af0, bf, acc[0][ct], 0, 0, 0);
            acc[1][ct] = __builtin_amdgcn_mfma_f32_16x16x32_bf16(af1, bf, acc[1][ct], 0, 0, 0);
        }
    }
#pragma unroll
    for (int ct = 0; ct < 2; ++ct) {
        int n = colbase + ct*16 + l15;
        float b2v = b2[n] * (float)K_;
#pragma unroll
        for (int rt = 0; rt < 2; ++rt)
#pragma unroll
            for (int r = 0; r < 4; ++r)
                agg_l[rt*16 + quad*4 + r][n] = f2b(acc[rt][ct][r] + b2v);
    }
    __syncthreads();

    // ---- GEMM2: t1 = silu([h | agg] @ u1 + u1b) -> s_l ----
#pragma unroll
    for (int rt = 0; rt < 2; ++rt)
#pragma unroll
        for (int ct = 0; ct < 2; ++ct) acc[rt][ct] = (f32x4){0.f,0.f,0.f,0.f};
#pragma unroll
    for (int kk = 0; kk < 8; ++kk) {
        const short (*src)[LDW] = (kk < 4) ? h_l : agg_l;
        int kloc = ((kk < 4) ? kk*32 : (kk-4)*32) + quad*8;
        short8 af0 = *(const short8*)&src[l15][kloc];
        short8 af1 = *(const short8*)&src[16 + l15][kloc];
#pragma unroll
        for (int ct = 0; ct < 2; ++ct) {
            int n = colbase + ct*16 + l15;
            short8 bf = *(const short8*)(wtu1 + (size_t)n*2*H_ + kk*32 + quad*8);
            acc[0][ct] = __builtin_amdgcn_mfma_f32_16x16x32_bf16(af0, bf, acc[0][ct], 0, 0, 0);
            acc[1][ct] = __builtin_amdgcn_mfma_f32_16x16x32_bf16(af1, bf, acc[1][ct], 0, 0, 0);
        }
    }
    __syncthreads();     // everyone done reading h_l/agg_l... and s_l from GEMM1 long done
#pragma unroll
    for (int ct = 0; ct < 2; ++ct) {
        int n = colbase + ct*16 + l15;
        float u1bv = u1b[n];
#pragma unroll
        for (int rt = 0; rt < 2; ++rt)
#pragma unroll
            for (int r = 0; r < 4; ++r)
                s_l[rt*16 + quad*4 + r][n] = f2b(silu_f(acc[rt][ct][r] + u1bv));
    }
    __syncthreads();

    // ---- GEMM3: upd = t1 @ u2 + u2b ; h += upd ----
#pragma unroll
    for (int rt = 0; rt < 2; ++rt)
#pragma unroll
        for (int ct = 0; ct < 2; ++ct) acc[rt][ct] = (f32x4){0.f,0.f,0.f,0.f};
#pragma unroll
    for (int kk = 0; kk < 4; ++kk) {
        int k0 = kk*32 + quad*8;
        short8 af0 = *(const short8*)&s_l[l15][k0];
        short8 af1 = *(const short8*)&s_l[16 + l15][k0];
#pragma unroll
        for (int ct = 0; ct < 2; ++ct) {
            int n = colbase + ct*16 + l15;
            short8 bf = *(const short8*)(wtu2 + (size_t)n*H_ + k0);
            acc[0][ct] = __builtin_amdgcn_mfma_f32_16x16x32_bf16(af0, bf, acc[0][ct], 0, 0, 0);
            acc[1][ct] = __builtin_amdgcn_mfma_f32_16x16x32_bf16(af1, bf, acc[1][ct], 0, 0, 0);
        }
    }
#pragma unroll
    for (int ct = 0; ct < 2; ++ct) {
        int n = colbase + ct*16 + l15;
        float u2bv = u2b[n];
#pragma unroll
        for (int rt = 0; rt < 2; ++rt)
#pragma unroll
            for (int r = 0; r < 4; ++r) {
                int m = rt*16 + quad*4 + r;
                size_t gi = (size_t)(node0+m)*H_ + n;
                h[gi] = h[gi] + acc[rt][ct][r] + u2bv;   // residual in fp32
            }
    }
}

// ---------------- out: out = h @ ow + ob ----------------
__global__ __launch_bounds__(256) void k_out(
    const float* __restrict__ h, const float* __restrict__ ow,
    const float* __restrict__ ob, float* __restrict__ out)
{
    int gid = blockIdx.x * 256 + threadIdx.x;  // BN_*8 threads
    int node = gid >> 3, o = gid & 7;
    if (o < OUT_) {
        float acc = ob[o];
        const float* hrow = h + (size_t)node*H_;
        for (int r = 0; r < H_; ++r)
            acc = fmaf(hrow[r], ow[r*OUT_ + o], acc);
        out[(size_t)node*OUT_ + o] = acc;
    }
}

extern "C" void kernel_launch(void* const* d_in, const int* in_sizes, int n_in,
                              void* d_out, int out_size, void* d_ws, size_t ws_size,
                              hipStream_t stream)
{
    const float* x   = (const float*)d_in[0];
    const float* ew  = (const float*)d_in[1];
    const float* eb  = (const float*)d_in[2];
    const float* miw = (const float*)d_in[3];   // (L,257,H)
    const float* mib = (const float*)d_in[4];   // (L,H)
    const float* mow = (const float*)d_in[5];   // (L,H,H)
    const float* mob = (const float*)d_in[6];   // (L,H)
    const float* uiw = (const float*)d_in[7];   // (L,2H,H)
    const float* uib = (const float*)d_in[8];   // (L,H)
    const float* uow = (const float*)d_in[9];   // (L,H,H)
    const float* uob = (const float*)d_in[10];  // (L,H)
    const float* ow  = (const float*)d_in[11];  // (H,OUT)
    const float* ob  = (const float*)d_in[12];  // (OUT)
    float* out = (float*)d_out;

    // workspace (bytes): h fp32 | nd fp32 | ni i32 | a bf16 | c bf16 | s bf16 | wt bf16
    char* w = (char*)d_ws;
    float* h  = (float*)w;                         w += (size_t)BN_*H_*4;   // 4 MB
    float* nd = (float*)w;                         w += (size_t)BN_*K_*4;   // 1 MB
    int*   ni = (int*)w;                           w += (size_t)BN_*K_*4;   // 1 MB
    short* a  = (short*)w;                         w += (size_t)BN_*H_*2;   // 2 MB
    short* c  = (short*)w;                         w += (size_t)BN_*H_*2;   // 2 MB
    short* s  = (short*)w;                         w += (size_t)BN_*H_*2;   // 2 MB
    short* wt = (short*)w;                                                  // 768 KB

    k_prep<<<(L_*LAYER_W)/256, 256, 0, stream>>>(miw, mow, uiw, uow, wt);
    k_embed<<<BN_*H_/256, 256, 0, stream>>>(x, ew, eb, h);
    k_knn<<<BN_/KNN_ROWS, 256, 0, stream>>>(x, ni, nd);
    for (int l = 0; l < L_; ++l) {
        const short* wl = wt + (size_t)l*LAYER_W;
        k_ac<<<BN_/MAC, 256, 0, stream>>>(h, wl + OFF_W1A, wl + OFF_W1C,
                                          mib + (size_t)l*H_, a, c);
        k_edge<<<BN_/ME, 256, 0, stream>>>((const unsigned*)a, (const unsigned*)c,
                                           ni, nd,
                                           miw + (size_t)l*257*H_ + 256*H_,
                                           (unsigned*)s);
        k_upd<<<BN_/MU, 256, 0, stream>>>(h, s,
                                          wl + OFF_W2, mob + (size_t)l*H_,
                                          wl + OFF_U1, uib + (size_t)l*H_,
                                          wl + OFF_U2, uob + (size_t)l*H_);
    }
    k_out<<<BN_*8/256, 256, 0, stream>>>(h, ow, ob, out);
}

// Round 4
// 327.356 us; speedup vs baseline: 1.6783x; 1.0340x over previous
//
#include <hip/hip_runtime.h>
#include <math.h>

#define B_ 4
#define N_ 2048
#define DIM_ 3
#define H_ 128
#define K_ 32
#define L_ 4
#define OUT_ 6
#define BN_ (B_*N_)

typedef __attribute__((ext_vector_type(8))) short short8;
typedef __attribute__((ext_vector_type(4))) float f32x4;

#define LDW (H_ + 8)          // padded LDS row (bf16 elems)
#define LAYER_W 98304         // shorts per layer: w1a 16K | w1c 16K | w2 16K | u1 32K | u2 16K
#define OFF_W1A 0
#define OFF_W1C 16384
#define OFF_W2  32768
#define OFF_U1  49152
#define OFF_U2  81920

__device__ __forceinline__ float silu_f(float x) {
    return __fdividef(x, 1.0f + __expf(-x));
}
__device__ __forceinline__ short f2b(float f) {          // fp32 -> bf16 RNE
    unsigned u = __float_as_uint(f);
    return (short)((u + 0x7FFFu + ((u >> 16) & 1u)) >> 16);
}
__device__ __forceinline__ float b2f(short s) {
    return __uint_as_float(((unsigned)(unsigned short)s) << 16);
}
__device__ __forceinline__ unsigned pack2(short lo, short hi) {
    return (unsigned)(unsigned short)lo | ((unsigned)(unsigned short)hi << 16);
}

// ---------------- prep: transpose+cast all layer weights to bf16 [n][k] ----------------
__global__ __launch_bounds__(256) void k_prep(
    const float* __restrict__ miw, const float* __restrict__ mow,
    const float* __restrict__ uiw, const float* __restrict__ uow,
    short* __restrict__ wt)
{
    int gid = blockIdx.x * 256 + threadIdx.x;      // L_*LAYER_W threads exactly
    int l = gid / LAYER_W, o = gid - l * LAYER_W;
    float v;
    if (o < OFF_W1C) {
        int n = o >> 7, k = o & 127;
        v = miw[(size_t)l*257*H_ + k*H_ + n];
    } else if (o < OFF_W2) {
        int oo = o - OFF_W1C, n = oo >> 7, k = oo & 127;
        v = miw[(size_t)l*257*H_ + (128 + k)*H_ + n];
    } else if (o < OFF_U1) {
        int oo = o - OFF_W2, n = oo >> 7, k = oo & 127;
        v = mow[(size_t)l*H_*H_ + k*H_ + n];
    } else if (o < OFF_U2) {
        int oo = o - OFF_U1, n = oo >> 8, k = oo & 255;
        v = uiw[(size_t)l*2*H_*H_ + k*H_ + n];
    } else {
        int oo = o - OFF_U2, n = oo >> 7, k = oo & 127;
        v = uow[(size_t)l*H_*H_ + k*H_ + n];
    }
    wt[gid] = f2b(v);
}

// ---------------- knn: radix-select top-K smallest d^2 per row ----------------
// One wave per row, 4 rows/block. hist is PER-WAVE private and DS ops from a
// wave retire in order -> NO barriers needed after the xs stage.
#define KNN_ROWS 4
__global__ __launch_bounds__(256) void k_knn(
    const float* __restrict__ x, int* __restrict__ nidx, float* __restrict__ ndist)
{
    __shared__ float xsx[N_], xsy[N_], xsz[N_];     // SoA: stride-1, conflict-free
    __shared__ int hist[KNN_ROWS][256];
    __shared__ int cnt_lt[KNN_ROWS], cnt_eq[KNN_ROWS];
    int b  = blockIdx.x / (N_/KNN_ROWS);
    int i0 = (blockIdx.x % (N_/KNN_ROWS)) * KNN_ROWS;
    const float* xb = x + (size_t)b*N_*3;
    for (int t = threadIdx.x; t < N_*3; t += 256) {
        float v = xb[t];
        int q = t / 3, r = t - q*3;
        float* dst = (r == 0) ? xsx : (r == 1) ? xsy : xsz;
        dst[q] = v;
    }
    __syncthreads();

    int wave = threadIdx.x >> 6, lane = threadIdx.x & 63;
    int i = i0 + wave;
    float xix = xsx[i], xiy = xsy[i], xiz = xsz[i];
    int* hrow = hist[wave];
    if (lane == 0) { cnt_lt[wave] = 0; cnt_eq[wave] = 0; }

    unsigned u[N_/64];
#pragma unroll
    for (int t = 0; t < N_/64; ++t) {
        int j = lane + 64*t;
        float d0 = xix-xsx[j], d1 = xiy-xsy[j], d2 = xiz-xsz[j];
        float d = d0*d0 + d1*d1 + d2*d2;
        u[t] = (j == i) ? 0x7F800000u : __float_as_uint(d);
    }

    unsigned prefix = 0, pmask = 0;
    int need = K_;
    for (int pass = 0; pass < 4; ++pass) {
        int s = 24 - pass*8;
        for (int bb = lane; bb < 256; bb += 64) hrow[bb] = 0;
#pragma unroll
        for (int t = 0; t < N_/64; ++t)
            if ((u[t] & pmask) == prefix)
                atomicAdd(&hrow[(u[t] >> s) & 255], 1);
        int c0 = hrow[lane*4+0], c1 = hrow[lane*4+1],
            c2 = hrow[lane*4+2], c3 = hrow[lane*4+3];
        int lsum = c0 + c1 + c2 + c3;
        int scan = lsum;
        for (int off = 1; off < 64; off <<= 1) {
            int o = __shfl_up(scan, off);
            if (lane >= off) scan += o;
        }
        int incl = scan, excl = incl - lsum;
        int D = -1, less = 0;
        if (excl < need && need <= incl) {
            if      (excl + c0 >= need)           { D = lane*4+0; less = excl; }
            else if (excl + c0 + c1 >= need)      { D = lane*4+1; less = excl + c0; }
            else if (excl + c0 + c1 + c2 >= need) { D = lane*4+2; less = excl + c0 + c1; }
            else                                  { D = lane*4+3; less = excl + c0 + c1 + c2; }
        }
        int packed = (D >= 0) ? ((D << 16) | less) : -1;
        for (int off = 32; off; off >>= 1)
            packed = max(packed, __shfl_xor(packed, off));
        D = packed >> 16; less = packed & 0xFFFF;
        prefix |= ((unsigned)D) << s;
        pmask  |= 0xFFu << s;
        need -= less;
    }
    int base_eq = K_ - need;
    size_t rbase = ((size_t)(b*N_ + i)) * K_;
#pragma unroll
    for (int t = 0; t < N_/64; ++t) {
        int pos = -1;
        if (u[t] < prefix) {
            pos = atomicAdd(&cnt_lt[wave], 1);
        } else if (u[t] == prefix) {
            int e = atomicAdd(&cnt_eq[wave], 1);
            if (e < need) pos = base_eq + e;
        }
        if (pos >= 0) {
            nidx[rbase + pos]  = lane + 64*t;
            ndist[rbase + pos] = sqrtf(__uint_as_float(u[t]));
        }
    }
}

// ---------------- shared a/c MFMA epilogue: from bf16 h in LDS ----------------
#define MAC 32
__device__ __forceinline__ void ac_mfma_from_lds(
    const short (*h_l)[LDW], int node0, int tid,
    const short* __restrict__ wt1a, const short* __restrict__ wt1c,
    const float* __restrict__ b1,
    short* __restrict__ a, short* __restrict__ c)
{
    int wave = tid >> 6, lane = tid & 63, l15 = lane & 15, quad = lane >> 4;
    f32x4 accA[2][2], accC[2][2];
#pragma unroll
    for (int rt = 0; rt < 2; ++rt)
#pragma unroll
        for (int ct = 0; ct < 2; ++ct) {
            accA[rt][ct] = (f32x4){0.f,0.f,0.f,0.f};
            accC[rt][ct] = (f32x4){0.f,0.f,0.f,0.f};
        }
    int colbase = wave * 32;
#pragma unroll
    for (int kk = 0; kk < 4; ++kk) {
        int k0 = kk*32 + quad*8;
        short8 af0 = *(const short8*)&h_l[l15][k0];
        short8 af1 = *(const short8*)&h_l[16 + l15][k0];
#pragma unroll
        for (int ct = 0; ct < 2; ++ct) {
            int n = colbase + ct*16 + l15;
            short8 bA = *(const short8*)(wt1a + (size_t)n*H_ + k0);
            short8 bC = *(const short8*)(wt1c + (size_t)n*H_ + k0);
            accA[0][ct] = __builtin_amdgcn_mfma_f32_16x16x32_bf16(af0, bA, accA[0][ct], 0, 0, 0);
            accA[1][ct] = __builtin_amdgcn_mfma_f32_16x16x32_bf16(af1, bA, accA[1][ct], 0, 0, 0);
            accC[0][ct] = __builtin_amdgcn_mfma_f32_16x16x32_bf16(af0, bC, accC[0][ct], 0, 0, 0);
            accC[1][ct] = __builtin_amdgcn_mfma_f32_16x16x32_bf16(af1, bC, accC[1][ct], 0, 0, 0);
        }
    }
#pragma unroll
    for (int ct = 0; ct < 2; ++ct) {
        int n = colbase + ct*16 + l15;
        float b1v = b1[n];
#pragma unroll
        for (int rt = 0; rt < 2; ++rt)
#pragma unroll
            for (int r = 0; r < 4; ++r) {
                int m = rt*16 + quad*4 + r;
                size_t gi = (size_t)(node0+m)*H_ + n;
                a[gi] = f2b(accA[rt][ct][r] + b1v);
                c[gi] = f2b(accC[rt][ct][r]);
            }
    }
}

// ---------------- embed + layer-0 a/c ----------------
__global__ __launch_bounds__(256) void k_embed_ac(
    const float* __restrict__ x, const float* __restrict__ ew,
    const float* __restrict__ eb,
    const short* __restrict__ wt1a, const short* __restrict__ wt1c,
    const float* __restrict__ b1,
    float* __restrict__ h, short* __restrict__ a, short* __restrict__ c)
{
    __shared__ __align__(16) short h_l[MAC][LDW];
    int node0 = blockIdx.x * MAC;
    int tid = threadIdx.x;
    for (int t = tid; t < MAC*H_; t += 256) {
        int row = t >> 7, ch = t & 127;
        int gr = node0 + row;
        float v = eb[ch];
        v = fmaf(x[gr*3+0], ew[ch], v);
        v = fmaf(x[gr*3+1], ew[H_+ch], v);
        v = fmaf(x[gr*3+2], ew[2*H_+ch], v);
        h[(size_t)gr*H_ + ch] = v;
        h_l[row][ch] = f2b(v);
    }
    __syncthreads();
    ac_mfma_from_lds(h_l, node0, tid, wt1a, wt1c, b1, a, c);
}

// ---------------- k_edge: s[m][ch] = sum_k silu(a_i + c_j + d*wd)  (bf16 out) ----------------
#define ME 8
__global__ __launch_bounds__(256) void k_edge(
    const unsigned* __restrict__ a2, const unsigned* __restrict__ c2,
    const int* __restrict__ nidx, const float* __restrict__ ndist,
    const float* __restrict__ wd, unsigned* __restrict__ s2)
{
    __shared__ int idx_s[ME][K_];
    __shared__ float dst_s[ME][K_];
    int node0 = blockIdx.x * ME;
    int tid = threadIdx.x;
    for (int t = tid; t < ME*K_; t += 256) {
        idx_s[t>>5][t&31] = nidx[(size_t)node0*K_ + t];
        dst_s[t>>5][t&31] = ndist[(size_t)node0*K_ + t];
    }
    __syncthreads();
    int c2i = tid & 63;
    int grp = tid >> 6;
    int ch0 = c2i * 2;
    float wd0 = wd[ch0], wd1 = wd[ch0+1];
    size_t cbase2 = (size_t)(node0 / N_) * N_ * (H_/2);
#pragma unroll
    for (int mm = 0; mm < 2; ++mm) {
        int m = grp*2 + mm;
        unsigned av = a2[(size_t)(node0+m)*(H_/2) + c2i];
        float a0 = b2f((short)(av & 0xFFFFu)), a1 = b2f((short)(av >> 16));
        float s0 = 0.f, s1 = 0.f;
#pragma unroll 8
        for (int k = 0; k < K_; ++k) {
            int j = idx_s[m][k];
            float dd = dst_s[m][k];
            unsigned cv = c2[cbase2 + (size_t)j*(H_/2) + c2i];
            float cv0 = b2f((short)(cv & 0xFFFFu)), cv1 = b2f((short)(cv >> 16));
            s0 += silu_f(a0 + fmaf(dd, wd0, cv0));
            s1 += silu_f(a1 + fmaf(dd, wd1, cv1));
        }
        s2[(size_t)(node0+m)*(H_/2) + c2i] = pack2(f2b(s0), f2b(s1));
    }
}

// ---------------- k_upd_ac (MFMA x3 + next-layer a/c): ----------------
#define MU 32
__global__ __launch_bounds__(256) void k_upd_ac(
    float* __restrict__ h, const short* __restrict__ s,
    const short* __restrict__ wt2, const float* __restrict__ b2,
    const short* __restrict__ wtu1, const float* __restrict__ u1b,
    const short* __restrict__ wtu2, const float* __restrict__ u2b,
    const short* __restrict__ wn1a, const short* __restrict__ wn1c,
    const float* __restrict__ b1n,
    short* __restrict__ a, short* __restrict__ c)
{
    __shared__ __align__(16) short s_l[MU][LDW];     // s; later reused for t1
    __shared__ __align__(16) short h_l[MU][LDW];     // old h; later new h
    __shared__ __align__(16) short agg_l[MU][LDW];
    int node0 = blockIdx.x * MU;
    int tid = threadIdx.x;
    for (int t = tid; t < MU*H_/4; t += 256) {
        float4 v = reinterpret_cast<const float4*>(h + (size_t)node0*H_)[t];
        int row = t >> 5, col = (t & 31) * 4;
        h_l[row][col+0] = f2b(v.x); h_l[row][col+1] = f2b(v.y);
        h_l[row][col+2] = f2b(v.z); h_l[row][col+3] = f2b(v.w);
    }
    for (int t = tid; t < MU*H_/2; t += 256) {
        unsigned v = reinterpret_cast<const unsigned*>(s + (size_t)node0*H_)[t];
        int row = t >> 6, col = (t & 63) * 2;
        s_l[row][col]   = (short)(v & 0xFFFFu);
        s_l[row][col+1] = (short)(v >> 16);
    }
    __syncthreads();

    int wave = tid >> 6, lane = tid & 63, l15 = lane & 15, quad = lane >> 4;
    int colbase = wave * 32;
    f32x4 acc[2][2];

    // ---- GEMM1: agg = s @ w2 + K*b2 ----
#pragma unroll
    for (int rt = 0; rt < 2; ++rt)
#pragma unroll
        for (int ct = 0; ct < 2; ++ct) acc[rt][ct] = (f32x4){0.f,0.f,0.f,0.f};
#pragma unroll
    for (int kk = 0; kk < 4; ++kk) {
        int k0 = kk*32 + quad*8;
        short8 af0 = *(const short8*)&s_l[l15][k0];
        short8 af1 = *(const short8*)&s_l[16 + l15][k0];
#pragma unroll
        for (int ct = 0; ct < 2; ++ct) {
            int n = colbase + ct*16 + l15;
            short8 bf = *(const short8*)(wt2 + (size_t)n*H_ + k0);
            acc[0][ct] = __builtin_amdgcn_mfma_f32_16x16x32_bf16(af0, bf, acc[0][ct], 0, 0, 0);
            acc[1][ct] = __builtin_amdgcn_mfma_f32_16x16x32_bf16(af1, bf, acc[1][ct], 0, 0, 0);
        }
    }
#pragma unroll
    for (int ct = 0; ct < 2; ++ct) {
        int n = colbase + ct*16 + l15;
        float b2v = b2[n] * (float)K_;
#pragma unroll
        for (int rt = 0; rt < 2; ++rt)
#pragma unroll
            for (int r = 0; r < 4; ++r)
                agg_l[rt*16 + quad*4 + r][n] = f2b(acc[rt][ct][r] + b2v);
    }
    __syncthreads();

    // ---- GEMM2: t1 = silu([h | agg] @ u1 + u1b) -> s_l ----
#pragma unroll
    for (int rt = 0; rt < 2; ++rt)
#pragma unroll
        for (int ct = 0; ct < 2; ++ct) acc[rt][ct] = (f32x4){0.f,0.f,0.f,0.f};
#pragma unroll
    for (int kk = 0; kk < 8; ++kk) {
        const short (*src)[LDW] = (kk < 4) ? h_l : agg_l;
        int kloc = ((kk < 4) ? kk*32 : (kk-4)*32) + quad*8;
        short8 af0 = *(const short8*)&src[l15][kloc];
        short8 af1 = *(const short8*)&src[16 + l15][kloc];
#pragma unroll
        for (int ct = 0; ct < 2; ++ct) {
            int n = colbase + ct*16 + l15;
            short8 bf = *(const short8*)(wtu1 + (size_t)n*2*H_ + kk*32 + quad*8);
            acc[0][ct] = __builtin_amdgcn_mfma_f32_16x16x32_bf16(af0, bf, acc[0][ct], 0, 0, 0);
            acc[1][ct] = __builtin_amdgcn_mfma_f32_16x16x32_bf16(af1, bf, acc[1][ct], 0, 0, 0);
        }
    }
    __syncthreads();     // all reads of h_l/agg_l done
#pragma unroll
    for (int ct = 0; ct < 2; ++ct) {
        int n = colbase + ct*16 + l15;
        float u1bv = u1b[n];
#pragma unroll
        for (int rt = 0; rt < 2; ++rt)
#pragma unroll
            for (int r = 0; r < 4; ++r)
                s_l[rt*16 + quad*4 + r][n] = f2b(silu_f(acc[rt][ct][r] + u1bv));
    }
    __syncthreads();

    // ---- GEMM3: upd = t1 @ u2 + u2b ; h += upd (fp32) ; h_l <- new h (bf16) ----
#pragma unroll
    for (int rt = 0; rt < 2; ++rt)
#pragma unroll
        for (int ct = 0; ct < 2; ++ct) acc[rt][ct] = (f32x4){0.f,0.f,0.f,0.f};
#pragma unroll
    for (int kk = 0; kk < 4; ++kk) {
        int k0 = kk*32 + quad*8;
        short8 af0 = *(const short8*)&s_l[l15][k0];
        short8 af1 = *(const short8*)&s_l[16 + l15][k0];
#pragma unroll
        for (int ct = 0; ct < 2; ++ct) {
            int n = colbase + ct*16 + l15;
            short8 bf = *(const short8*)(wtu2 + (size_t)n*H_ + k0);
            acc[0][ct] = __builtin_amdgcn_mfma_f32_16x16x32_bf16(af0, bf, acc[0][ct], 0, 0, 0);
            acc[1][ct] = __builtin_amdgcn_mfma_f32_16x16x32_bf16(af1, bf, acc[1][ct], 0, 0, 0);
        }
    }
#pragma unroll
    for (int ct = 0; ct < 2; ++ct) {
        int n = colbase + ct*16 + l15;
        float u2bv = u2b[n];
#pragma unroll
        for (int rt = 0; rt < 2; ++rt)
#pragma unroll
            for (int r = 0; r < 4; ++r) {
                int m = rt*16 + quad*4 + r;
                size_t gi = (size_t)(node0+m)*H_ + n;
                float nh = h[gi] + acc[rt][ct][r] + u2bv;
                h[gi] = nh;
                h_l[m][n] = f2b(nh);
            }
    }
    // ---- next layer's a/c from the new h ----
    if (wn1a) {
        __syncthreads();
        ac_mfma_from_lds(h_l, node0, tid, wn1a, wn1c, b1n, a, c);
    }
}

// ---------------- out: out = h @ ow + ob ----------------
__global__ __launch_bounds__(256) void k_out(
    const float* __restrict__ h, const float* __restrict__ ow,
    const float* __restrict__ ob, float* __restrict__ out)
{
    int gid = blockIdx.x * 256 + threadIdx.x;  // BN_*8 threads
    int node = gid >> 3, o = gid & 7;
    if (o < OUT_) {
        float acc = ob[o];
        const float* hrow = h + (size_t)node*H_;
        for (int r = 0; r < H_; ++r)
            acc = fmaf(hrow[r], ow[r*OUT_ + o], acc);
        out[(size_t)node*OUT_ + o] = acc;
    }
}

extern "C" void kernel_launch(void* const* d_in, const int* in_sizes, int n_in,
                              void* d_out, int out_size, void* d_ws, size_t ws_size,
                              hipStream_t stream)
{
    const float* x   = (const float*)d_in[0];
    const float* ew  = (const float*)d_in[1];
    const float* eb  = (const float*)d_in[2];
    const float* miw = (const float*)d_in[3];   // (L,257,H)
    const float* mib = (const float*)d_in[4];   // (L,H)
    const float* mow = (const float*)d_in[5];   // (L,H,H)
    const float* mob = (const float*)d_in[6];   // (L,H)
    const float* uiw = (const float*)d_in[7];   // (L,2H,H)
    const float* uib = (const float*)d_in[8];   // (L,H)
    const float* uow = (const float*)d_in[9];   // (L,H,H)
    const float* uob = (const float*)d_in[10];  // (L,H)
    const float* ow  = (const float*)d_in[11];  // (H,OUT)
    const float* ob  = (const float*)d_in[12];  // (OUT)
    float* out = (float*)d_out;

    // workspace: h fp32 | nd fp32 | ni i32 | a bf16 | c bf16 | s bf16 | wt bf16
    char* w = (char*)d_ws;
    float* h  = (float*)w;                         w += (size_t)BN_*H_*4;
    float* nd = (float*)w;                         w += (size_t)BN_*K_*4;
    int*   ni = (int*)w;                           w += (size_t)BN_*K_*4;
    short* a  = (short*)w;                         w += (size_t)BN_*H_*2;
    short* c  = (short*)w;                         w += (size_t)BN_*H_*2;
    short* s  = (short*)w;                         w += (size_t)BN_*H_*2;
    short* wt = (short*)w;

    k_prep<<<(L_*LAYER_W)/256, 256, 0, stream>>>(miw, mow, uiw, uow, wt);
    k_embed_ac<<<BN_/MAC, 256, 0, stream>>>(x, ew, eb,
        wt + OFF_W1A, wt + OFF_W1C, mib, h, a, c);
    k_knn<<<BN_/KNN_ROWS, 256, 0, stream>>>(x, ni, nd);
    for (int l = 0; l < L_; ++l) {
        const short* wl = wt + (size_t)l*LAYER_W;
        const short* wn = (l+1 < L_) ? wt + (size_t)(l+1)*LAYER_W : nullptr;
        k_edge<<<BN_/ME, 256, 0, stream>>>((const unsigned*)a, (const unsigned*)c,
                                           ni, nd,
                                           miw + (size_t)l*257*H_ + 256*H_,
                                           (unsigned*)s);
        k_upd_ac<<<BN_/MU, 256, 0, stream>>>(h, s,
            wl + OFF_W2, mob + (size_t)l*H_,
            wl + OFF_U1, uib + (size_t)l*H_,
            wl + OFF_U2, uob + (size_t)l*H_,
            wn ? wn + OFF_W1A : nullptr, wn ? wn + OFF_W1C : nullptr,
            wn ? mib + (size_t)(l+1)*H_ : nullptr,
            a, c);
    }
    k_out<<<BN_*8/256, 256, 0, stream>>>(h, ow, ob, out);
}